// Round 1
// baseline (4353.237 us; speedup 1.0000x reference)
//
#include <hip/hip_runtime.h>
#include <hip/hip_fp16.h>

typedef _Float16 f16;
typedef _Float16 f16x2 __attribute__((ext_vector_type(2)));
typedef _Float16 f16x8 __attribute__((ext_vector_type(8)));
typedef float    f32x4 __attribute__((ext_vector_type(4)));

#define BN_EPS 1e-5f

static constexpr int BB  = 32;    // batch
static constexpr int CC  = 128;   // channels (= K of GEMM1)
static constexpr int HWN = 1024;  // H*W = L
static constexpr int RIN = 256;
static constexpr int RH  = 512;
static constexpr int OCN = 128;
static constexpr int MM  = BB * HWN;  // 32768

// ---------------------------------------------------------------- BN stats
__global__ void bn_stats_kernel(const float* __restrict__ x,
                                const float* __restrict__ gamma,
                                const float* __restrict__ beta,
                                float* __restrict__ scale,
                                float* __restrict__ shift) {
    int c = blockIdx.x;
    int tid = threadIdx.x;
    float s = 0.f, s2 = 0.f;
    const float* xc = x + (size_t)c * HWN;
    for (int idx = tid; idx < BB * HWN; idx += 256) {
        int b = idx >> 10, hw = idx & 1023;
        float v = xc[(size_t)b * (CC * HWN) + hw];
        s += v; s2 += v * v;
    }
    for (int off = 32; off > 0; off >>= 1) {
        s  += __shfl_down(s, off, 64);
        s2 += __shfl_down(s2, off, 64);
    }
    __shared__ float ls[4], ls2[4];
    int wv = tid >> 6, ln = tid & 63;
    if (ln == 0) { ls[wv] = s; ls2[wv] = s2; }
    __syncthreads();
    if (tid == 0) {
        float ts  = ls[0] + ls[1] + ls[2] + ls[3];
        float ts2 = ls2[0] + ls2[1] + ls2[2] + ls2[3];
        const float inv_n = 1.0f / (BB * HWN);
        float mean = ts * inv_n;
        float var  = ts2 * inv_n - mean * mean;
        float rstd = rsqrtf(var + BN_EPS);
        float sc = gamma[c] * rstd;
        scale[c] = sc;
        shift[c] = beta[c] - mean * sc;
    }
}

// ------------------------------------------- normalize + transpose -> A1 f16
// A1[(b*HW + hw) * C + c] = norm(x[b][c][hw])
__global__ void prep_x_kernel(const float* __restrict__ x,
                              const float* __restrict__ scale,
                              const float* __restrict__ shift,
                              f16* __restrict__ A1) {
    __shared__ float tile[32][33];
    int tx = threadIdx.x, ty = threadIdx.y;  // 32 x 8
    int hb = blockIdx.x, cb = blockIdx.y, b = blockIdx.z;
    #pragma unroll
    for (int k = 0; k < 4; k++) {
        int c  = cb * 32 + ty + 8 * k;
        int hw = hb * 32 + tx;
        tile[ty + 8 * k][tx] = x[(size_t)b * (CC * HWN) + (size_t)c * HWN + hw];
    }
    __syncthreads();
    #pragma unroll
    for (int k = 0; k < 4; k++) {
        int hw = hb * 32 + ty + 8 * k;
        int c  = cb * 32 + tx;
        float v = tile[tx][ty + 8 * k];
        A1[(size_t)(b * HWN + hw) * CC + c] = (f16)(v * scale[c] + shift[c]);
    }
}

// ------------------------------------------------------------ weight prep
// w_* -> f16 (same [N][K] layout); W_hh -> paired layout Wt2[i2][j] = (W[j][2i2], W[j][2i2+1])
__global__ void prep_w_kernel(const float* __restrict__ w_in,
                              const float* __restrict__ w_ih,
                              const float* __restrict__ w_out,
                              const float* __restrict__ w_hh,
                              const float* __restrict__ b_ih,
                              const float* __restrict__ b_hh,
                              f16* __restrict__ w_in_h,
                              f16* __restrict__ w_ih_h,
                              f16* __restrict__ w_out_h,
                              f16x2* __restrict__ whh2,
                              float* __restrict__ bihh) {
    int idx = blockIdx.x * 256 + threadIdx.x;
    if (idx < 32768) { w_in_h[idx] = (f16)w_in[idx]; return; }
    idx -= 32768;
    if (idx < 131072) { w_ih_h[idx] = (f16)w_ih[idx]; return; }
    idx -= 131072;
    if (idx < 65536) { w_out_h[idx] = (f16)w_out[idx]; return; }
    idx -= 65536;
    if (idx < 131072) {
        int i2 = idx >> 9, j = idx & 511;
        f16x2 v;
        v[0] = (f16)w_hh[(size_t)j * 512 + 2 * i2];
        v[1] = (f16)w_hh[(size_t)j * 512 + 2 * i2 + 1];
        whh2[idx] = v;
        return;
    }
    idx -= 131072;
    if (idx < 512) bihh[idx] = b_ih[idx] + b_hh[idx];
}

// ------------------------------------------------------------- MFMA GEMM
// C[M,N] = A[M,K] * W[N,K]^T + bias ; per-wave 64x64 tile, LDS-free.
// MODE 0: tanhshrink(val) -> f16 out   (GEMM1)
// MODE 1: val -> f16 out               (GEMM2)
// MODE 2: val -> f32 out, transposed store to (B, OC, HW)  (GEMM3)
template <int MODE>
__global__ void gemm_kernel(const f16* __restrict__ A,
                            const f16* __restrict__ W,
                            const float* __restrict__ bias,
                            void* __restrict__ outp,
                            int N, int K) {
    int wave = threadIdx.x >> 6;
    int lane = threadIdx.x & 63;
    int q = lane >> 4, r = lane & 15;
    int bm = blockIdx.x * 256 + wave * 64;
    int bn = blockIdx.y * 64;

    f32x4 acc[4][4];
    #pragma unroll
    for (int i = 0; i < 4; i++)
        #pragma unroll
        for (int j = 0; j < 4; j++)
            acc[i][j] = (f32x4){0.f, 0.f, 0.f, 0.f};

    const f16* Ap = A + (size_t)(bm + r) * K + 8 * q;
    const f16* Wp = W + (size_t)(bn + r) * K + 8 * q;

    for (int k = 0; k < K; k += 32) {
        f16x8 av[4], bv[4];
        #pragma unroll
        for (int i = 0; i < 4; i++)
            av[i] = *(const f16x8*)(Ap + (size_t)(16 * i) * K + k);
        #pragma unroll
        for (int i = 0; i < 4; i++)
            bv[i] = *(const f16x8*)(Wp + (size_t)(16 * i) * K + k);
        #pragma unroll
        for (int mi = 0; mi < 4; mi++)
            #pragma unroll
            for (int ni = 0; ni < 4; ni++)
                acc[mi][ni] = __builtin_amdgcn_mfma_f32_16x16x32_f16(
                    av[mi], bv[ni], acc[mi][ni], 0, 0, 0);
    }

    #pragma unroll
    for (int mi = 0; mi < 4; mi++) {
        #pragma unroll
        for (int ni = 0; ni < 4; ni++) {
            int col = bn + 16 * ni + r;
            float bval = bias[col];
            #pragma unroll
            for (int i = 0; i < 4; i++) {
                int row = bm + 16 * mi + 4 * q + i;
                float val = acc[mi][ni][i] + bval;
                if (MODE == 0) {
                    val = val - tanhf(val);
                    ((f16*)outp)[(size_t)row * N + col] = (f16)val;
                } else if (MODE == 1) {
                    ((f16*)outp)[(size_t)row * N + col] = (f16)val;
                } else {
                    int b = row >> 10, hw = row & 1023;
                    ((float*)outp)[(size_t)b * (OCN * HWN) + (size_t)col * HWN + hw] = val;
                }
            }
        }
    }
}

// ---------------------------------------------------------------- RNN scan
// one WG per batch chain; W_hh streamed from L2 (f16 paired layout); h in LDS.
__device__ __forceinline__ float dot2acc(unsigned int w, f16x2 h, float c) {
#if __has_builtin(__builtin_amdgcn_fdot2)
    return __builtin_amdgcn_fdot2(__builtin_bit_cast(f16x2, w), h, c, false);
#else
    f16x2 a = __builtin_bit_cast(f16x2, w);
    return c + (float)a[0] * (float)h[0] + (float)a[1] * (float)h[1];
#endif
}

__global__ __launch_bounds__(1024) void rnn_kernel(const uint4* __restrict__ Wt2,
                                                   const f16* __restrict__ xg,
                                                   f16* __restrict__ hs) {
    int b = blockIdx.x;
    int t = threadIdx.x;
    int jg = t & 127;   // output rows j0 = 4*jg .. +3
    int sl = t >> 7;    // 8 K-slices of 32 i-pairs each

    __shared__ __align__(16) f16   hbuf[512];
    __shared__ __align__(16) float part[8][512];

    if (t < 512) hbuf[t] = (f16)0.f;
    __syncthreads();

    const uint4* wbase = Wt2 + (size_t)(sl * 32) * 128 + jg;
    const f16* xgb = xg + (size_t)b * HWN * RH;
    f16* hsb = hs + (size_t)b * HWN * RH;
    const unsigned int* hp = (const unsigned int*)hbuf;

    for (int step = 0; step < HWN; step++) {
        float a0 = 0.f, a1 = 0.f, a2 = 0.f, a3 = 0.f;
        const uint4* wp = wbase;
        #pragma unroll 8
        for (int n = 0; n < 32; n++) {
            uint4 w = *wp;
            wp += 128;                        // next i-pair (512 half2 = 128 uint4)
            f16x2 hh = __builtin_bit_cast(f16x2, hp[sl * 32 + n]);
            a0 = dot2acc(w.x, hh, a0);
            a1 = dot2acc(w.y, hh, a1);
            a2 = dot2acc(w.z, hh, a2);
            a3 = dot2acc(w.w, hh, a3);
        }
        f32x4 pv = {a0, a1, a2, a3};
        *(f32x4*)&part[sl][4 * jg] = pv;
        __syncthreads();
        if (t < 512) {
            float y = 0.f;
            #pragma unroll
            for (int s = 0; s < 8; s++) y += part[s][t];
            float xv = (float)xgb[(size_t)step * RH + t];
            float h = tanhf(y + xv);
            hsb[(size_t)step * RH + t] = (f16)h;
            hbuf[t] = (f16)h;
        }
        __syncthreads();
    }
}

// ------------------------------------------------------------------ launch
extern "C" void kernel_launch(void* const* d_in, const int* in_sizes, int n_in,
                              void* d_out, int out_size, void* d_ws, size_t ws_size,
                              hipStream_t stream) {
    const float* x     = (const float*)d_in[0];
    const float* gamma = (const float*)d_in[1];
    const float* beta  = (const float*)d_in[2];
    const float* w_in  = (const float*)d_in[3];
    const float* b_in  = (const float*)d_in[4];
    const float* w_ih  = (const float*)d_in[5];
    const float* b_ih  = (const float*)d_in[6];
    const float* w_hh  = (const float*)d_in[7];
    const float* b_hh  = (const float*)d_in[8];
    const float* w_out = (const float*)d_in[9];
    const float* b_out = (const float*)d_in[10];

    char* ws = (char*)d_ws;
    // small region (< 1 MB)
    float* scale   = (float*)(ws + 0);        //   512 B
    float* shift   = (float*)(ws + 512);      //   512 B
    float* bihh    = (float*)(ws + 1024);     //  2 KB
    f16*   w_in_h  = (f16*)(ws + 4096);       // 64 KB
    f16*   w_ih_h  = (f16*)(ws + 69632);      // 256 KB
    f16*   w_out_h = (f16*)(ws + 331776);     // 128 KB
    f16x2* whh2    = (f16x2*)(ws + 462848);   // 512 KB  (ends 987136)
    // xgate: 32768*512*2 = 32 MB
    f16* xgate = (f16*)(ws + (1 << 20));
    // big region (32 MB): A1 (8 MB) + inp (16 MB) live until gemm2; hs aliases whole region
    char* big = ws + (1 << 20) + 33554432;
    f16* A1  = (f16*)big;                 // [32768][128]
    f16* inp = (f16*)(big + 8388608);     // [32768][256]
    f16* hs  = (f16*)big;                 // [32768][512]  (A1/inp dead by then)
    // total ws usage: 68157440 bytes

    bn_stats_kernel<<<128, 256, 0, stream>>>(x, gamma, beta, scale, shift);
    prep_w_kernel<<<1410, 256, 0, stream>>>(w_in, w_ih, w_out, w_hh, b_ih, b_hh,
                                            w_in_h, w_ih_h, w_out_h, whh2, bihh);
    prep_x_kernel<<<dim3(32, 4, 32), dim3(32, 8), 0, stream>>>(x, scale, shift, A1);
    gemm_kernel<0><<<dim3(128, 4), 256, 0, stream>>>(A1, w_in_h, b_in, (void*)inp, RIN, CC);
    gemm_kernel<1><<<dim3(128, 8), 256, 0, stream>>>(inp, w_ih_h, bihh, (void*)xgate, RH, RIN);
    rnn_kernel<<<32, 1024, 0, stream>>>((const uint4*)whh2, xgate, hs);
    gemm_kernel<2><<<dim3(128, 2), 256, 0, stream>>>(hs, w_out_h, b_out, d_out, OCN, RH);
}